// Round 4
// baseline (167.002 us; speedup 1.0000x reference)
//
#include <hip/hip_runtime.h>

#define NB 4
#define NT 2048
#define ND 512
#define NH 8
#define NHD 64

typedef __attribute__((ext_vector_type(4))) float f32x4;
typedef __attribute__((ext_vector_type(8))) short bf16x8;
typedef __attribute__((ext_vector_type(4))) short bf16x4;
typedef __attribute__((ext_vector_type(4))) unsigned int u32x4;
typedef __attribute__((ext_vector_type(2))) unsigned int u32x2;

__device__ __forceinline__ unsigned short f2bf(float f) {
    unsigned u = __builtin_bit_cast(unsigned, f);
    u += 0x7FFFu + ((u >> 16) & 1u);
    return (unsigned short)(u >> 16);
}
__device__ __forceinline__ float bf2f(unsigned short h) {
    unsigned u = ((unsigned)h) << 16;
    return __builtin_bit_cast(float, u);
}
__device__ __forceinline__ float exp2_fast(float x) {
    float r;
    asm("v_exp_f32 %0, %1" : "=v"(r) : "v"(x));
    return r;
}
__device__ __forceinline__ unsigned cvt_pk_bf16(float lo, float hi) {
    unsigned r;
    asm("v_cvt_pk_bf16_f32 %0, %1, %2" : "=v"(r) : "v"(lo), "v"(hi));
    return r;
}

#define GLOAD16(g, s)                                                          \
    __builtin_amdgcn_global_load_lds(                                          \
        (const __attribute__((address_space(1))) unsigned int*)(g),            \
        (__attribute__((address_space(3))) unsigned int*)(s), 16, 0, 0)

// ---------------- fp32 -> bf16 convert (contiguous) ----------------
__global__ __launch_bounds__(256) void k_cvt(const float* __restrict__ in,
                                             unsigned short* __restrict__ out, int n8) {
    int i = blockIdx.x * 256 + threadIdx.x;
    if (i >= n8) return;
    const float* p = in + (long)i * 8;
    f32x4 a = *(const f32x4*)p;
    f32x4 b = *(const f32x4*)(p + 4);
    bf16x8 o;
#pragma unroll
    for (int e = 0; e < 4; e++) {
        o[e] = (short)f2bf(a[e]);
        o[e + 4] = (short)f2bf(b[e]);
    }
    *(bf16x8*)(out + (long)i * 8) = o;
}

// ---------------- fp32 [R][C] -> bf16 [C][R] transpose ----------------
__global__ __launch_bounds__(256) void k_tr(const float* __restrict__ in,
                                            unsigned short* __restrict__ out, int R, int C) {
    __shared__ unsigned short tile[32][33];
    int c0 = blockIdx.x * 32, r0 = blockIdx.y * 32;
    int tx = threadIdx.x, ty = threadIdx.y;
#pragma unroll
    for (int j = 0; j < 32; j += 8)
        tile[ty + j][tx] = f2bf(in[(long)(r0 + ty + j) * C + c0 + tx]);
    __syncthreads();
#pragma unroll
    for (int j = 0; j < 32; j += 8)
        out[(long)(c0 + ty + j) * R + r0 + tx] = tile[tx][ty + j];
}

// ---------------- bf16 GEMM: C[M,N] = A[M,K] * Bt[N,K]^T ----------------
// 128x128x64 tile, 4 waves, GLOAD16 staging (pre-swizzled source, linear LDS
// dest, XOR-swizzled reads), single-buffered, 2 barriers/K-step (m97 pattern).
// 1-D grid, XCD-pinned by m-panel.
template <int EPI>
__global__ __launch_bounds__(256) void k_gemm(const unsigned short* __restrict__ A,
                                              const unsigned short* __restrict__ Bt,
                                              float* __restrict__ outf,
                                              unsigned short* __restrict__ q,
                                              unsigned short* __restrict__ kk_,
                                              unsigned short* __restrict__ vt,
                                              int M, int N, int K) {
    __shared__ unsigned short Al[128 * 64];
    __shared__ unsigned short Bl[128 * 64];
    int id = blockIdx.x;
    int xcd = id & 7, s = id >> 3;
    int ytile = (s & 7) * 8 + xcd;  // m-tile: pinned to xcd (64 m-tiles)
    int xtile = s >> 3;             // n-tile
    int m0 = ytile * 128, n0 = xtile * 128;
    int tid = threadIdx.x;
    int w = tid >> 6, l = tid & 63;
    int wm = (w >> 1) * 64, wn = (w & 1) * 64;
    int lr = l & 15, lg = l >> 4;
    int lrow8 = l >> 3, lch = l & 7;
    int chg = lch ^ lrow8;  // inverse-swizzled source chunk (row&7 == lrow8)

    f32x4 acc[4][4];
#pragma unroll
    for (int i = 0; i < 4; i++)
#pragma unroll
        for (int j = 0; j < 4; j++) acc[i][j] = (f32x4){0.f, 0.f, 0.f, 0.f};

    for (int k0 = 0; k0 < K; k0 += 64) {
        __syncthreads();  // prev tile's readers done
#pragma unroll
        for (int p = 0; p < 4; p++) {
            int br = p * 32 + w * 8;  // wave-uniform base row
            int row = br + lrow8;
            GLOAD16(A + (long)(m0 + row) * K + k0 + chg * 8, &Al[br * 64]);
            GLOAD16(Bt + (long)(n0 + row) * K + k0 + chg * 8, &Bl[br * 64]);
        }
        __syncthreads();  // vmcnt(0) drain: tile staged
#pragma unroll
        for (int kc = 0; kc < 2; kc++) {
            bf16x8 af[4], bff[4];
#pragma unroll
            for (int i = 0; i < 4; i++) {
                int row = wm + i * 16 + lr;
                int ch = (kc * 4 + lg) ^ (row & 7);
                af[i] = *(const bf16x8*)(Al + row * 64 + ch * 8);
                int rowb = wn + i * 16 + lr;
                int chb = (kc * 4 + lg) ^ (rowb & 7);
                bff[i] = *(const bf16x8*)(Bl + rowb * 64 + chb * 8);
            }
#pragma unroll
            for (int i = 0; i < 4; i++)
#pragma unroll
                for (int j = 0; j < 4; j++)
                    acc[i][j] = __builtin_amdgcn_mfma_f32_16x16x32_bf16(af[i], bff[j], acc[i][j], 0, 0, 0);
        }
    }

    if (EPI == 0) {
#pragma unroll
        for (int i = 0; i < 4; i++)
#pragma unroll
            for (int j = 0; j < 4; j++) {
                int row = m0 + wm + i * 16 + lg * 4;
                int col = n0 + wn + j * 16 + lr;
#pragma unroll
                for (int r = 0; r < 4; r++) outf[(long)(row + r) * N + col] = acc[i][j][r];
            }
    } else {
#pragma unroll
        for (int i = 0; i < 4; i++)
#pragma unroll
            for (int j = 0; j < 4; j++) {
                int m = m0 + wm + i * 16 + lg * 4;
                int col = n0 + wn + j * 16 + lr;
                int sel = col >> 9;
                int cc = col & 511;
                int h = cc >> 6, hd = cc & 63;
                int b = m >> 11, t = m & 2047;
                long bh = (long)(b * NH + h);
                if (sel == 0) {
#pragma unroll
                    for (int r = 0; r < 4; r++)
                        q[(bh * NT + t + r) * NHD + hd] = f2bf(acc[i][j][r]);
                } else if (sel == 1) {
#pragma unroll
                    for (int r = 0; r < 4; r++)
                        kk_[(bh * NT + t + r) * NHD + hd] = f2bf(acc[i][j][r]);
                } else {
                    bf16x4 pk;
#pragma unroll
                    for (int r = 0; r < 4; r++) pk[r] = (short)f2bf(acc[i][j][r]);
                    *(bf16x4*)(vt + (bh * NHD + hd) * NT + t) = pk;
                }
            }
    }
}

// ---------------- flash attention (causal), bf16 MFMA, v4 ----------------
// QBLK=64 as 2 waves x 32 q-rows (2 column-blocks per wave): K/V fragment
// loads hoisted over the qb loop -> same LDS reads feed 2x MFMA. Grid 1024,
// XCD-pinned (bh%8 == block%8, 4 heads/XCD -> L2-resident K/V), longest-first.
// GLOAD16 double-buffered staging, 1 barrier/tile. Diagonal-only mask,
// exp2-domain softmax, defer-max, cvt_pk packing, setprio around MFMA.
__global__ __launch_bounds__(128, 2) void k_attn(const unsigned short* __restrict__ qb,
                                                 const unsigned short* __restrict__ kb,
                                                 const unsigned short* __restrict__ vtb,
                                                 unsigned short* __restrict__ yb) {
    __shared__ unsigned short Kl[2][64 * 64];
    __shared__ unsigned short Vl[2][64 * 64];  // V^T tile: rows d(64), cols t(64)
    __shared__ unsigned short Pl[4 * 16 * 64]; // slot (w*2+qb): 16q x 64t

    int id = blockIdx.x;
    int xcd = id & 7, s = id >> 3;          // s in [0,128)
    int bh = (s & 3) * 8 + xcd;             // 4 heads per XCD
    int qt = 31 - (s >> 2);                 // longest first
    int q0 = qt * 64;
    int nkt = qt + 1;

    int tid = threadIdx.x, w = tid >> 6, l = tid & 63;
    int lr = l & 15, lg = l >> 4;
    int lrow8 = l >> 3, lch = l & 7;
    int chg = lch ^ lrow8;  // inverse-swizzled global chunk for linear LDS dest
    long hbase = (long)bh * NT * NHD;
    const float QSCALE = 0.125f * 1.4426950408889634f;  // 1/sqrt(64) * log2(e)

    // Q fragments (B-operand), scaled; qb-block: q = q0 + w*32 + qb*16 + lr
    bf16x8 qf[2][2];
#pragma unroll
    for (int qbk = 0; qbk < 2; qbk++) {
        int qrow = q0 + w * 32 + qbk * 16 + lr;
#pragma unroll
        for (int dh = 0; dh < 2; dh++) {
            bf16x8 v = *(const bf16x8*)(qb + hbase + (long)qrow * NHD + dh * 32 + lg * 8);
#pragma unroll
            for (int e = 0; e < 8; e++) v[e] = (short)f2bf(bf2f((unsigned short)v[e]) * QSCALE);
            qf[qbk][dh] = v;
        }
    }

    float mrun[2] = {-__builtin_inff(), -__builtin_inff()};
    float ell[2] = {0.f, 0.f};
    f32x4 ot[2][4];
#pragma unroll
    for (int qbk = 0; qbk < 2; qbk++)
#pragma unroll
        for (int i = 0; i < 4; i++) ot[qbk][i] = (f32x4){0.f, 0.f, 0.f, 0.f};

    // stage tile 0 -> buf 0 (wave w stages rows [w*32, w*32+32) of K and V^T)
#pragma unroll
    for (int j = 0; j < 4; j++) {
        int br = w * 32 + j * 8;
        GLOAD16(kb + hbase + (long)(br + lrow8) * NHD + chg * 8, &Kl[0][br * 64]);
        GLOAD16(vtb + hbase + (long)(br + lrow8) * NT + chg * 8, &Vl[0][br * 64]);
    }

    for (int kt = 0; kt < nkt; kt++) {
        int b = kt & 1;
        __syncthreads();  // drains vmcnt(0): tile kt's DMA complete, rendezvous
        if (kt + 1 < nkt) {
            int k0s = (kt + 1) * 64;
#pragma unroll
            for (int j = 0; j < 4; j++) {
                int br = w * 32 + j * 8;
                GLOAD16(kb + hbase + (long)(k0s + br + lrow8) * NHD + chg * 8,
                        &Kl[b ^ 1][br * 64]);
                GLOAD16(vtb + hbase + (long)(br + lrow8) * NT + k0s + chg * 8,
                        &Vl[b ^ 1][br * 64]);
            }
        }
        int k0 = kt * 64;
        const unsigned short* Kb = Kl[b];
        const unsigned short* Vb = Vl[b];

        // S^T = mfma(K, Q): K-frag loaded once, used by both q-blocks
        f32x4 st[2][4];
        __builtin_amdgcn_s_setprio(1);
#pragma unroll
        for (int sub = 0; sub < 4; sub++) {
            f32x4 z0 = (f32x4){0.f, 0.f, 0.f, 0.f};
            f32x4 z1 = (f32x4){0.f, 0.f, 0.f, 0.f};
#pragma unroll
            for (int dh = 0; dh < 2; dh++) {
                int row = sub * 16 + lr;
                int ch = (dh * 4 + lg) ^ (row & 7);
                bf16x8 kf = *(const bf16x8*)(Kb + row * 64 + ch * 8);
                z0 = __builtin_amdgcn_mfma_f32_16x16x32_bf16(kf, qf[0][dh], z0, 0, 0, 0);
                z1 = __builtin_amdgcn_mfma_f32_16x16x32_bf16(kf, qf[1][dh], z1, 0, 0, 0);
            }
            st[0][sub] = z0;
            st[1][sub] = z1;
        }
        __builtin_amdgcn_s_setprio(0);

        // causal mask: only the last k-tile can have t > q
        if (kt == nkt - 1) {
#pragma unroll
            for (int qbk = 0; qbk < 2; qbk++) {
                int qg = q0 + w * 32 + qbk * 16 + lr;
#pragma unroll
                for (int sub = 0; sub < 4; sub++)
#pragma unroll
                    for (int r = 0; r < 4; r++) {
                        int tg = k0 + sub * 16 + lg * 4 + r;
                        if (tg > qg) st[qbk][sub][r] = -__builtin_inff();
                    }
            }
        }

        // row(q) max per q-block: 16 in-lane + reduce across lg groups
        float pmax[2];
#pragma unroll
        for (int qbk = 0; qbk < 2; qbk++) {
            float pm = st[qbk][0][0];
#pragma unroll
            for (int sub = 0; sub < 4; sub++)
#pragma unroll
                for (int r = 0; r < 4; r++) pm = fmaxf(pm, st[qbk][sub][r]);
            pm = fmaxf(pm, __shfl_xor(pm, 16));
            pm = fmaxf(pm, __shfl_xor(pm, 32));
            pmax[qbk] = pm;
        }

        // defer-max: one vote for both q-blocks
        bool ok = (pmax[0] - mrun[0] <= 8.f) && (pmax[1] - mrun[1] <= 8.f);
        if (!__all(ok)) {
#pragma unroll
            for (int qbk = 0; qbk < 2; qbk++) {
                float mn = fmaxf(mrun[qbk], pmax[qbk]);
                float alpha = exp2_fast(mrun[qbk] - mn);
                ell[qbk] *= alpha;
#pragma unroll
                for (int sub = 0; sub < 4; sub++) ot[qbk][sub] *= alpha;
                mrun[qbk] = mn;
            }
        }

        // P = exp2(S - m), pack to bf16, stash per (wave, q-block) in LDS
#pragma unroll
        for (int qbk = 0; qbk < 2; qbk++) {
            float psum = 0.f;
            unsigned short* Ps = Pl + (w * 2 + qbk) * 1024;
#pragma unroll
            for (int sub = 0; sub < 4; sub++) {
                float p0 = exp2_fast(st[qbk][sub][0] - mrun[qbk]);
                float p1 = exp2_fast(st[qbk][sub][1] - mrun[qbk]);
                float p2 = exp2_fast(st[qbk][sub][2] - mrun[qbk]);
                float p3 = exp2_fast(st[qbk][sub][3] - mrun[qbk]);
                psum += (p0 + p1) + (p2 + p3);
                u32x2 pw;
                pw[0] = cvt_pk_bf16(p0, p1);
                pw[1] = cvt_pk_bf16(p2, p3);
                int t = sub * 16 + lg * 4;
                int ch = t >> 3;
                *(u32x2*)(Ps + lr * 64 + ((ch ^ (lr & 7)) * 8) + (t & 7)) = pw;
            }
            psum += __shfl_xor(psum, 16);
            psum += __shfl_xor(psum, 32);
            ell[qbk] += psum;
        }

        // PV: O^T[d][q] += V^T[d][t] * P^T[t][q]; V-frag shared by q-blocks
        bf16x8 pf[2][2];
#pragma unroll
        for (int qbk = 0; qbk < 2; qbk++)
#pragma unroll
            for (int th = 0; th < 2; th++) {
                int ch = (th * 4 + lg) ^ (lr & 7);
                pf[qbk][th] = *(const bf16x8*)(Pl + (w * 2 + qbk) * 1024 + lr * 64 + ch * 8);
            }
        __builtin_amdgcn_s_setprio(1);
#pragma unroll
        for (int md = 0; md < 4; md++) {
#pragma unroll
            for (int th = 0; th < 2; th++) {
                int row = md * 16 + lr;
                int ch = (th * 4 + lg) ^ (row & 7);
                bf16x8 vf = *(const bf16x8*)(Vb + row * 64 + ch * 8);
                ot[0][md] = __builtin_amdgcn_mfma_f32_16x16x32_bf16(vf, pf[0][th], ot[0][md], 0, 0, 0);
                ot[1][md] = __builtin_amdgcn_mfma_f32_16x16x32_bf16(vf, pf[1][th], ot[1][md], 0, 0, 0);
            }
        }
        __builtin_amdgcn_s_setprio(0);
    }

#pragma unroll
    for (int qbk = 0; qbk < 2; qbk++) {
        float inv = 1.f / ell[qbk];
        long yrow = (long)((bh >> 3) * NT + q0 + w * 32 + qbk * 16 + lr);
        int hcol = (bh & 7) * NHD;
#pragma unroll
        for (int sub = 0; sub < 4; sub++) {
            bf16x4 o;
#pragma unroll
            for (int r = 0; r < 4; r++) o[r] = (short)f2bf(ot[qbk][sub][r] * inv);
            *(bf16x4*)(yb + yrow * ND + hcol + sub * 16 + lg * 4) = o;
        }
    }
}

extern "C" void kernel_launch(void* const* d_in, const int* in_sizes, int n_in,
                              void* d_out, int out_size, void* d_ws, size_t ws_size,
                              hipStream_t stream) {
    const float* x = (const float*)d_in[0];
    // d_in[1] = attn_mask (causal tril by construction; hardcoded)
    const float* Wqkv = (const float*)d_in[2];
    const float* Wout = (const float*)d_in[3];

    char* ws = (char*)d_ws;
    unsigned short* xb = (unsigned short*)(ws);                        // [8192][512]
    unsigned short* wqkvt = (unsigned short*)(ws + 8388608);           // [1536][512]
    unsigned short* woutt = (unsigned short*)(ws + 8388608 + 1572864); // [512][512]
    unsigned short* qbp = (unsigned short*)(ws + 10485760);            // [b,h,t,hd]
    unsigned short* kbp = (unsigned short*)(ws + 10485760 + 8388608);  // [b,h,t,hd]
    unsigned short* vtb = (unsigned short*)(ws + 10485760 + 16777216); // [b,h,hd,t]
    unsigned short* yb = xb;  // reuse x's slot after GEMM1
    float* out = (float*)d_out;

    k_cvt<<<dim3(2048), dim3(256), 0, stream>>>(x, xb, (NB * NT * ND) / 8);
    k_tr<<<dim3(48, 16), dim3(32, 8), 0, stream>>>(Wqkv, wqkvt, 512, 1536);
    k_tr<<<dim3(16, 16), dim3(32, 8), 0, stream>>>(Wout, woutt, 512, 512);
    k_gemm<1><<<dim3(768), dim3(256), 0, stream>>>(xb, wqkvt, nullptr, qbp, kbp, vtb,
                                                   NB * NT, 3 * ND, ND);
    k_attn<<<dim3(1024), dim3(128), 0, stream>>>(qbp, kbp, vtb, yb);
    k_gemm<0><<<dim3(256), dim3(256), 0, stream>>>(yb, woutt, out, nullptr, nullptr, nullptr,
                                                   NB * NT, ND, ND);
}

// Round 5
// 149.408 us; speedup vs baseline: 1.1178x; 1.1178x over previous
//
#include <hip/hip_runtime.h>

#define NB 4
#define NT 2048
#define ND 512
#define NH 8
#define NHD 64

typedef __attribute__((ext_vector_type(4))) float f32x4;
typedef __attribute__((ext_vector_type(8))) short bf16x8;
typedef __attribute__((ext_vector_type(4))) short bf16x4;
typedef __attribute__((ext_vector_type(4))) unsigned int u32x4;
typedef __attribute__((ext_vector_type(2))) unsigned int u32x2;

__device__ __forceinline__ unsigned short f2bf(float f) {
    unsigned u = __builtin_bit_cast(unsigned, f);
    u += 0x7FFFu + ((u >> 16) & 1u);
    return (unsigned short)(u >> 16);
}
__device__ __forceinline__ float bf2f(unsigned short h) {
    unsigned u = ((unsigned)h) << 16;
    return __builtin_bit_cast(float, u);
}
__device__ __forceinline__ float exp2_fast(float x) {
    float r;
    asm("v_exp_f32 %0, %1" : "=v"(r) : "v"(x));
    return r;
}
__device__ __forceinline__ unsigned cvt_pk_bf16(float lo, float hi) {
    unsigned r;
    asm("v_cvt_pk_bf16_f32 %0, %1, %2" : "=v"(r) : "v"(lo), "v"(hi));
    return r;
}

#define GLOAD16(g, s)                                                          \
    __builtin_amdgcn_global_load_lds(                                          \
        (const __attribute__((address_space(1))) unsigned int*)(g),            \
        (__attribute__((address_space(3))) unsigned int*)(s), 16, 0, 0)

// ---------------- fused prep: cvt(x) + tr(Wqkv) + tr(Wout) ----------------
// blocks [0,2048): cvt; [2048,2816): tr Wqkv (48x16); [2816,3072): tr Wout (16x16)
__global__ __launch_bounds__(256) void k_prep(const float* __restrict__ x,
                                              const float* __restrict__ Wqkv,
                                              const float* __restrict__ Wout,
                                              unsigned short* __restrict__ xb,
                                              unsigned short* __restrict__ wqkvt,
                                              unsigned short* __restrict__ woutt) {
    __shared__ unsigned short tile[32][33];
    int id = blockIdx.x;
    if (id < 2048) {
        int i = id * 256 + threadIdx.x;
        const float* p = x + (long)i * 8;
        f32x4 a = *(const f32x4*)p;
        f32x4 b = *(const f32x4*)(p + 4);
        bf16x8 o;
#pragma unroll
        for (int e = 0; e < 4; e++) {
            o[e] = (short)f2bf(a[e]);
            o[e + 4] = (short)f2bf(b[e]);
        }
        *(bf16x8*)(xb + (long)i * 8) = o;
        return;
    }
    const float* in;
    unsigned short* out;
    int R, C, bx, by;
    if (id < 2816) {
        int t = id - 2048;
        in = Wqkv; out = wqkvt; R = 512; C = 1536;
        bx = t % 48; by = t / 48;
    } else {
        int t = id - 2816;
        in = Wout; out = woutt; R = 512; C = 512;
        bx = t % 16; by = t / 16;
    }
    int c0 = bx * 32, r0 = by * 32;
    int tx = threadIdx.x & 31, ty = threadIdx.x >> 5;
#pragma unroll
    for (int j = 0; j < 32; j += 8)
        tile[ty + j][tx] = f2bf(in[(long)(r0 + ty + j) * C + c0 + tx]);
    __syncthreads();
#pragma unroll
    for (int j = 0; j < 32; j += 8)
        out[(long)(c0 + ty + j) * R + r0 + tx] = tile[tx][ty + j];
}

// ---------------- bf16 GEMM1: qkv = xb * Wqkv^T, scatter epilogue ----------
// 128x128x64 tile, 4 waves, GLOAD16 staging (pre-swizzled source, linear LDS
// dest, XOR-swizzled reads), single-buffered m97 pattern, XCD-pinned m-panels.
__global__ __launch_bounds__(256) void k_gemm1(const unsigned short* __restrict__ A,
                                               const unsigned short* __restrict__ Bt,
                                               unsigned short* __restrict__ q,
                                               unsigned short* __restrict__ kk_,
                                               unsigned short* __restrict__ vt,
                                               int K, int N) {
    __shared__ unsigned short Al[128 * 64];
    __shared__ unsigned short Bl[128 * 64];
    int id = blockIdx.x;
    int xcd = id & 7, s = id >> 3;
    int ytile = (s & 7) * 8 + xcd;  // m-tile pinned to xcd (64 m-tiles)
    int xtile = s >> 3;             // n-tile
    int m0 = ytile * 128, n0 = xtile * 128;
    int tid = threadIdx.x;
    int w = tid >> 6, l = tid & 63;
    int wm = (w >> 1) * 64, wn = (w & 1) * 64;
    int lr = l & 15, lg = l >> 4;
    int lrow8 = l >> 3, lch = l & 7;
    int chg = lch ^ lrow8;

    f32x4 acc[4][4];
#pragma unroll
    for (int i = 0; i < 4; i++)
#pragma unroll
        for (int j = 0; j < 4; j++) acc[i][j] = (f32x4){0.f, 0.f, 0.f, 0.f};

    for (int k0 = 0; k0 < K; k0 += 64) {
        __syncthreads();
#pragma unroll
        for (int p = 0; p < 4; p++) {
            int br = p * 32 + w * 8;
            int row = br + lrow8;
            GLOAD16(A + (long)(m0 + row) * K + k0 + chg * 8, &Al[br * 64]);
            GLOAD16(Bt + (long)(n0 + row) * K + k0 + chg * 8, &Bl[br * 64]);
        }
        __syncthreads();
#pragma unroll
        for (int kc = 0; kc < 2; kc++) {
            bf16x8 af[4], bff[4];
#pragma unroll
            for (int i = 0; i < 4; i++) {
                int row = wm + i * 16 + lr;
                int ch = (kc * 4 + lg) ^ (row & 7);
                af[i] = *(const bf16x8*)(Al + row * 64 + ch * 8);
                int rowb = wn + i * 16 + lr;
                int chb = (kc * 4 + lg) ^ (rowb & 7);
                bff[i] = *(const bf16x8*)(Bl + rowb * 64 + chb * 8);
            }
#pragma unroll
            for (int i = 0; i < 4; i++)
#pragma unroll
                for (int j = 0; j < 4; j++)
                    acc[i][j] = __builtin_amdgcn_mfma_f32_16x16x32_bf16(af[i], bff[j], acc[i][j], 0, 0, 0);
        }
    }

#pragma unroll
    for (int i = 0; i < 4; i++)
#pragma unroll
        for (int j = 0; j < 4; j++) {
            int m = m0 + wm + i * 16 + lg * 4;
            int col = n0 + wn + j * 16 + lr;
            int sel = col >> 9;
            int cc = col & 511;
            int h = cc >> 6, hd = cc & 63;
            int b = m >> 11, t = m & 2047;
            long bh = (long)(b * NH + h);
            if (sel == 0) {
#pragma unroll
                for (int r = 0; r < 4; r++)
                    q[(bh * NT + t + r) * NHD + hd] = f2bf(acc[i][j][r]);
            } else if (sel == 1) {
#pragma unroll
                for (int r = 0; r < 4; r++)
                    kk_[(bh * NT + t + r) * NHD + hd] = f2bf(acc[i][j][r]);
            } else {
                bf16x4 pk;
#pragma unroll
                for (int r = 0; r < 4; r++) pk[r] = (short)f2bf(acc[i][j][r]);
                *(bf16x4*)(vt + (bh * NHD + hd) * NT + t) = pk;
            }
        }
}

// ---------------- bf16 GEMM2: out = yb * Wout^T (fp32 out) ----------------
// 64x128x64 tile -> 512 blocks (2/CU). Double-buffered GLOAD16 (stage next
// before compute, 1 barrier/iter) so DMA hides under MFMA at low occupancy.
__global__ __launch_bounds__(256) void k_gemm2(const unsigned short* __restrict__ A,
                                               const unsigned short* __restrict__ Bt,
                                               float* __restrict__ outf,
                                               int K, int N) {
    __shared__ unsigned short Al[2][64 * 64];
    __shared__ unsigned short Bl[2][128 * 64];
    int id = blockIdx.x;
    int xcd = id & 7, s = id >> 3;          // s in [0,64)
    int ytile = (s & 15) * 8 + xcd;         // 128 m-tiles, pinned to xcd
    int xtile = s >> 4;                     // 4 n-tiles
    int m0 = ytile * 64, n0 = xtile * 128;
    int tid = threadIdx.x;
    int w = tid >> 6, l = tid & 63;
    int wm = (w >> 1) * 32, wn = (w & 1) * 64;
    int lr = l & 15, lg = l >> 4;
    int lrow8 = l >> 3, lch = l & 7;
    int chg = lch ^ lrow8;

    f32x4 acc[2][4];
#pragma unroll
    for (int i = 0; i < 2; i++)
#pragma unroll
        for (int j = 0; j < 4; j++) acc[i][j] = (f32x4){0.f, 0.f, 0.f, 0.f};

    // prologue: stage k0=0 into buf 0
#pragma unroll
    for (int j = 0; j < 2; j++) {
        int br = w * 16 + j * 8;
        GLOAD16(A + (long)(m0 + br + lrow8) * K + chg * 8, &Al[0][br * 64]);
    }
#pragma unroll
    for (int j = 0; j < 4; j++) {
        int br = w * 32 + j * 8;
        GLOAD16(Bt + (long)(n0 + br + lrow8) * K + chg * 8, &Bl[0][br * 64]);
    }

    int nk = K / 64;
    for (int kt = 0; kt < nk; kt++) {
        int cur = kt & 1;
        __syncthreads();  // drains DMA for buf[cur]; readers done with buf[cur^1]
        if (kt + 1 < nk) {
            int k0 = (kt + 1) * 64;
#pragma unroll
            for (int j = 0; j < 2; j++) {
                int br = w * 16 + j * 8;
                GLOAD16(A + (long)(m0 + br + lrow8) * K + k0 + chg * 8, &Al[cur ^ 1][br * 64]);
            }
#pragma unroll
            for (int j = 0; j < 4; j++) {
                int br = w * 32 + j * 8;
                GLOAD16(Bt + (long)(n0 + br + lrow8) * K + k0 + chg * 8, &Bl[cur ^ 1][br * 64]);
            }
        }
        const unsigned short* Ab = Al[cur];
        const unsigned short* Bb = Bl[cur];
#pragma unroll
        for (int kc = 0; kc < 2; kc++) {
            bf16x8 af[2], bff[4];
#pragma unroll
            for (int i = 0; i < 2; i++) {
                int row = wm + i * 16 + lr;
                int ch = (kc * 4 + lg) ^ (row & 7);
                af[i] = *(const bf16x8*)(Ab + row * 64 + ch * 8);
            }
#pragma unroll
            for (int j = 0; j < 4; j++) {
                int rowb = wn + j * 16 + lr;
                int chb = (kc * 4 + lg) ^ (rowb & 7);
                bff[j] = *(const bf16x8*)(Bb + rowb * 64 + chb * 8);
            }
#pragma unroll
            for (int i = 0; i < 2; i++)
#pragma unroll
                for (int j = 0; j < 4; j++)
                    acc[i][j] = __builtin_amdgcn_mfma_f32_16x16x32_bf16(af[i], bff[j], acc[i][j], 0, 0, 0);
        }
    }

#pragma unroll
    for (int i = 0; i < 2; i++)
#pragma unroll
        for (int j = 0; j < 4; j++) {
            int row = m0 + wm + i * 16 + lg * 4;
            int col = n0 + wn + j * 16 + lr;
#pragma unroll
            for (int r = 0; r < 4; r++) outf[(long)(row + r) * N + col] = acc[i][j][r];
        }
}

// ---------------- flash attention (causal), bf16 MFMA, v3 (proven) --------
// QBLK=64 (4 waves x 16 q-rows), KVBLK=64, one q-tile per block. Grid 1024,
// XCD-pinned (bh%8 == block%8, 4 heads/XCD -> L2-resident K/V), longest-first.
// GLOAD16 double-buffered staging, 1 barrier/tile. Diagonal-only causal mask,
// exp2-domain softmax, defer-max (THR=8), cvt_pk packing, setprio around MFMA.
__global__ __launch_bounds__(256, 4) void k_attn(const unsigned short* __restrict__ qb,
                                                 const unsigned short* __restrict__ kb,
                                                 const unsigned short* __restrict__ vtb,
                                                 unsigned short* __restrict__ yb) {
    __shared__ unsigned short Kl[2][64 * 64];
    __shared__ unsigned short Vl[2][64 * 64];  // V^T tile: rows d(64), cols t(64)
    __shared__ unsigned short Pl[4 * 16 * 64];

    int id = blockIdx.x;
    int xcd = id & 7, s = id >> 3;          // s in [0,128)
    int bh = (s & 3) * 8 + xcd;             // 4 heads per XCD
    int qt = 31 - (s >> 2);                 // longest first
    int q0 = qt * 64;
    int nkt = qt + 1;

    int tid = threadIdx.x, w = tid >> 6, l = tid & 63;
    int lr = l & 15, lg = l >> 4;
    int lrow8 = l >> 3, lch = l & 7;
    int chg = lch ^ lrow8;  // inverse-swizzled global chunk for linear LDS dest
    long hbase = (long)bh * NT * NHD;
    const float QSCALE = 0.125f * 1.4426950408889634f;  // 1/sqrt(64) * log2(e)

    // Q fragments (B-operand), scaled
    int qrow = q0 + w * 16 + lr;
    bf16x8 qf[2];
#pragma unroll
    for (int dh = 0; dh < 2; dh++) {
        bf16x8 v = *(const bf16x8*)(qb + hbase + (long)qrow * NHD + dh * 32 + lg * 8);
#pragma unroll
        for (int e = 0; e < 8; e++) v[e] = (short)f2bf(bf2f((unsigned short)v[e]) * QSCALE);
        qf[dh] = v;
    }

    float mrun = -__builtin_inff(), ell = 0.f;
    f32x4 ot[4];
#pragma unroll
    for (int i = 0; i < 4; i++) ot[i] = (f32x4){0.f, 0.f, 0.f, 0.f};

    // stage tile 0 -> buf 0 (wave w stages rows [w*16, w*16+16) of K and V^T)
    {
#pragma unroll
        for (int j = 0; j < 2; j++) {
            int br = w * 16 + j * 8;
            GLOAD16(kb + hbase + (long)(br + lrow8) * NHD + chg * 8, &Kl[0][br * 64]);
            GLOAD16(vtb + hbase + (long)(br + lrow8) * NT + chg * 8, &Vl[0][br * 64]);
        }
    }

    for (int kt = 0; kt < nkt; kt++) {
        int b = kt & 1;
        __syncthreads();  // drains vmcnt(0): tile kt's DMA complete, rendezvous
        if (kt + 1 < nkt) {
            int k0s = (kt + 1) * 64;
#pragma unroll
            for (int j = 0; j < 2; j++) {
                int br = w * 16 + j * 8;
                GLOAD16(kb + hbase + (long)(k0s + br + lrow8) * NHD + chg * 8,
                        &Kl[b ^ 1][br * 64]);
                GLOAD16(vtb + hbase + (long)(br + lrow8) * NT + k0s + chg * 8,
                        &Vl[b ^ 1][br * 64]);
            }
        }
        int k0 = kt * 64;
        const unsigned short* Kb = Kl[b];
        const unsigned short* Vb = Vl[b];

        // S^T = mfma(K, Q): rows t (4 subtiles of 16), col q = lr
        f32x4 st[4];
        __builtin_amdgcn_s_setprio(1);
#pragma unroll
        for (int sub = 0; sub < 4; sub++) {
            f32x4 z = (f32x4){0.f, 0.f, 0.f, 0.f};
#pragma unroll
            for (int dh = 0; dh < 2; dh++) {
                int row = sub * 16 + lr;
                int ch = (dh * 4 + lg) ^ (row & 7);
                bf16x8 kf = *(const bf16x8*)(Kb + row * 64 + ch * 8);
                z = __builtin_amdgcn_mfma_f32_16x16x32_bf16(kf, qf[dh], z, 0, 0, 0);
            }
            st[sub] = z;
        }
        __builtin_amdgcn_s_setprio(0);

        // causal mask: only the last k-tile can have t > q
        if (kt == nkt - 1) {
            int qg = q0 + w * 16 + lr;
#pragma unroll
            for (int sub = 0; sub < 4; sub++)
#pragma unroll
                for (int r = 0; r < 4; r++) {
                    int tg = k0 + sub * 16 + lg * 4 + r;
                    if (tg > qg) st[sub][r] = -__builtin_inff();
                }
        }

        // row(q) max: 16 in-lane + reduce across lg groups
        float pmax = st[0][0];
#pragma unroll
        for (int sub = 0; sub < 4; sub++)
#pragma unroll
            for (int r = 0; r < 4; r++) pmax = fmaxf(pmax, st[sub][r]);
        pmax = fmaxf(pmax, __shfl_xor(pmax, 16));
        pmax = fmaxf(pmax, __shfl_xor(pmax, 32));

        // defer-max: skip rescale while tile max growth <= 8 (log2 units)
        if (!__all(pmax - mrun <= 8.f)) {
            float mn = fmaxf(mrun, pmax);
            float alpha = exp2_fast(mrun - mn);
            ell *= alpha;
#pragma unroll
            for (int sub = 0; sub < 4; sub++) ot[sub] *= alpha;
            mrun = mn;
        }

        // P = exp2(S - m), pack to bf16, stash per-wave in LDS
        float psum = 0.f;
#pragma unroll
        for (int sub = 0; sub < 4; sub++) {
            float p0 = exp2_fast(st[sub][0] - mrun);
            float p1 = exp2_fast(st[sub][1] - mrun);
            float p2 = exp2_fast(st[sub][2] - mrun);
            float p3 = exp2_fast(st[sub][3] - mrun);
            psum += (p0 + p1) + (p2 + p3);
            u32x2 pw;
            pw[0] = cvt_pk_bf16(p0, p1);
            pw[1] = cvt_pk_bf16(p2, p3);
            int t = sub * 16 + lg * 4;
            int ch = t >> 3;
            *(u32x2*)(Pl + w * 1024 + lr * 64 + ((ch ^ (lr & 7)) * 8) + (t & 7)) = pw;
        }
        psum += __shfl_xor(psum, 16);
        psum += __shfl_xor(psum, 32);
        ell += psum;

        // PV: O^T[d][q] += V^T[d][t] * P^T[t][q]  (per-wave Pl, no barrier)
        bf16x8 pf[2];
#pragma unroll
        for (int th = 0; th < 2; th++) {
            int ch = (th * 4 + lg) ^ (lr & 7);
            pf[th] = *(const bf16x8*)(Pl + w * 1024 + lr * 64 + ch * 8);
        }
        __builtin_amdgcn_s_setprio(1);
#pragma unroll
        for (int md = 0; md < 4; md++) {
#pragma unroll
            for (int th = 0; th < 2; th++) {
                int row = md * 16 + lr;
                int ch = (th * 4 + lg) ^ (row & 7);
                bf16x8 vf = *(const bf16x8*)(Vb + row * 64 + ch * 8);
                ot[md] = __builtin_amdgcn_mfma_f32_16x16x32_bf16(vf, pf[th], ot[md], 0, 0, 0);
            }
        }
        __builtin_amdgcn_s_setprio(0);
    }

    float inv = 1.f / ell;
    long yrow = (long)((bh >> 3) * NT + q0 + w * 16 + lr);
    int hcol = (bh & 7) * NHD;
#pragma unroll
    for (int sub = 0; sub < 4; sub++) {
        bf16x4 o;
#pragma unroll
        for (int r = 0; r < 4; r++) o[r] = (short)f2bf(ot[sub][r] * inv);
        *(bf16x4*)(yb + yrow * ND + hcol + sub * 16 + lg * 4) = o;
    }
}

extern "C" void kernel_launch(void* const* d_in, const int* in_sizes, int n_in,
                              void* d_out, int out_size, void* d_ws, size_t ws_size,
                              hipStream_t stream) {
    const float* x = (const float*)d_in[0];
    // d_in[1] = attn_mask (causal tril by construction; hardcoded)
    const float* Wqkv = (const float*)d_in[2];
    const float* Wout = (const float*)d_in[3];

    char* ws = (char*)d_ws;
    unsigned short* xb = (unsigned short*)(ws);                        // [8192][512]
    unsigned short* wqkvt = (unsigned short*)(ws + 8388608);           // [1536][512]
    unsigned short* woutt = (unsigned short*)(ws + 8388608 + 1572864); // [512][512]
    unsigned short* qbp = (unsigned short*)(ws + 10485760);            // [b,h,t,hd]
    unsigned short* kbp = (unsigned short*)(ws + 10485760 + 8388608);  // [b,h,t,hd]
    unsigned short* vtb = (unsigned short*)(ws + 10485760 + 16777216); // [b,h,hd,t]
    unsigned short* yb = xb;  // reuse x's slot after GEMM1
    float* out = (float*)d_out;

    k_prep<<<dim3(3072), dim3(256), 0, stream>>>(x, Wqkv, Wout, xb, wqkvt, woutt);
    k_gemm1<<<dim3(768), dim3(256), 0, stream>>>(xb, wqkvt, qbp, kbp, vtb, ND, 3 * ND);
    k_attn<<<dim3(1024), dim3(256), 0, stream>>>(qbp, kbp, vtb, yb);
    k_gemm2<<<dim3(512), dim3(256), 0, stream>>>(yb, woutt, out, ND, ND);
}